// Round 3
// baseline (49.126 us; speedup 1.0000x reference)
//
#include <hip/hip_runtime.h>

// buckets = gray( packbits( mat[row,:] @ proj[:,r] > 0 ) ),  gray(b) = b ^ (b>>1)
// mat: [2,32,8192,64] f32   proj: [64,8] f32   out: [524288] i32
//
// Persistent 2-wave blocks. Each wave owns a double-buffered 2x16 KiB LDS slice
// and processes 4 tiles of 64 rows. Pipeline: issue tile t+1's 16
// global_load_lds_dwordx4 (each 1 KiB, fully coalesced), s_waitcnt vmcnt(16)
// (drains tile t only), compute tile t from LDS while t+1 streams in.
// Bank-conflict swizzle applied on the per-lane GLOBAL source address (chunk k
// of row r lands at float4-slot k ^ (r&7)); readback applies the same XOR.

constexpr int D     = 64;
constexpr int R     = 8;
constexpr int ROWS  = 2 * 32 * 8192;     // 524288
constexpr int TILES = ROWS / 64;         // 8192 wave-tiles
constexpr int NBLK  = 1024;
constexpr int WAVES = NBLK * 2;          // 2048 waves
constexpr int TPW   = TILES / WAVES;     // 4 tiles per wave

__global__ __launch_bounds__(128) void lsh_kernel(
    const float* __restrict__ mat,
    const float* __restrict__ proj,
    int*         __restrict__ out)
{
    __shared__ float lds[2 * 2 * 64 * D];          // [wave][buf][64*64] = 64 KiB
    const int lane  = threadIdx.x & 63;
    const int wid   = threadIdx.x >> 6;
    const int gwave = blockIdx.x * 2 + wid;
    float* waveLds  = lds + wid * (2 * 64 * D);

    const int rl0 = lane >> 4;                     // row-local base (+4 per load)
    const int ks0 = lane & 15;                     // chunk base before swizzle

    auto issue = [&](int tile, int buf) {
        const int rowBase = tile * 64;
        float* dst = waveLds + buf * (64 * D);
        #pragma unroll
        for (int i = 0; i < 16; ++i) {
            const int r  = i * 4 + rl0;            // row-local 0..63
            const int ks = ks0 ^ (r & 7);          // swizzled source chunk
            const float* src = mat + ((size_t)(rowBase + r) * D + ks * 4);
            __builtin_amdgcn_global_load_lds(
                (const __attribute__((address_space(1))) void*)src,
                (__attribute__((address_space(3))) void*)(dst + i * 256),
                16, 0, 0);
        }
    };

    issue(gwave, 0);                               // prologue: tile 0 -> buf 0

    #pragma unroll 1
    for (int it = 0; it < TPW; ++it) {
        if (it + 1 < TPW) {
            issue(gwave + (it + 1) * WAVES, (it + 1) & 1);
            asm volatile("s_waitcnt vmcnt(16)" ::: "memory");   // tile it landed
        } else {
            asm volatile("s_waitcnt vmcnt(0)" ::: "memory");
        }

        const float* buf = waveLds + (it & 1) * (64 * D);
        float s[R] = {0.f, 0.f, 0.f, 0.f, 0.f, 0.f, 0.f, 0.f};
        #pragma unroll
        for (int k = 0; k < 16; ++k) {
            const int slot = lane * 16 + (k ^ (lane & 7));      // float4 slot
            const float4 v = *reinterpret_cast<const float4*>(&buf[slot * 4]);
            const float vv[4] = {v.x, v.y, v.z, v.w};
            #pragma unroll
            for (int j = 0; j < 4; ++j) {
                const int d = k * 4 + j;
                #pragma unroll
                for (int r = 0; r < R; ++r)
                    s[r] = fmaf(vv[j], proj[d * R + r], s[r]);  // proj: SGPR operand
            }
        }

        int bin = 0;
        #pragma unroll
        for (int r = 0; r < R; ++r)
            bin |= (s[r] > 0.0f) ? (1 << r) : 0;
        const int bucket = bin ^ (bin >> 1);       // Gray-code table, analytically

        out[(gwave + it * WAVES) * 64 + lane] = bucket;
    }
}

extern "C" void kernel_launch(void* const* d_in, const int* in_sizes, int n_in,
                              void* d_out, int out_size, void* d_ws, size_t ws_size,
                              hipStream_t stream) {
    const float* mat  = (const float*)d_in[0];   // [2,32,8192,64] f32
    const float* proj = (const float*)d_in[1];   // [1,1,64,8] f32
    // d_in[2] = perm (== gray code, computed analytically), d_in[3] = enc_vec
    int* out = (int*)d_out;                      // [524288] i32

    lsh_kernel<<<NBLK, 128, 0, stream>>>(mat, proj, out);
}

// Round 4
// 29.789 us; speedup vs baseline: 1.6492x; 1.6492x over previous
//
#include <hip/hip_runtime.h>

// buckets = gray( packbits( mat[row,:] @ proj[:,r] > 0 ) ),  gray(b) = b ^ (b>>1)
// mat: [2,32,8192,64] f32   proj: [64,8] f32   out: [524288] i32
//
// LDS-free design: 16 lanes cooperate per row. One global_load_dwordx4 per
// wave covers a "group" of 4 rows (1 KiB, perfectly coalesced): lane = row
// (lane>>4) x chunk (lane&15). Each lane computes 8 partial dots against its
// private 32-VGPR proj fragment, then a value-splitting DPP butterfly
// (xor7, xor2, xor8 splits + xor1 final) leaves lane h holding the FULL dot
// for r = 4*h2 + 2*h1 + h3. One __ballot then carries the sign bits of all
// 4 rows; bin = (w & 0x55) | ((w>>7) & 0xAA) per 16-bit ballot slice.

constexpr int D      = 64;
constexpr int ROWS   = 2 * 32 * 8192;      // 524288
constexpr int GROUPS = ROWS / 4;           // 131072 (4 rows / group)
constexpr int NBLK   = 2048;
constexpr int WPB    = 4;                  // 256 threads = 4 waves
constexpr int GPW    = GROUPS / (NBLK * WPB);  // 16 groups per wave
constexpr int U      = 4;                  // register prefetch depth

#define DPP_XOR1 0xB1    // quad_perm [1,0,3,2]
#define DPP_XOR2 0x4E    // quad_perm [2,3,0,1]
#define DPP_XOR7 0x141   // row_half_mirror
#define DPP_XOR8 0x128   // row_ror:8  (rotate by 8 within 16 == xor 8)

template <int CTRL>
__device__ __forceinline__ float dppf(float x) {
    const int xi = __float_as_int(x);
    const int r = __builtin_amdgcn_update_dpp(xi, xi, CTRL, 0xF, 0xF, false);
    return __int_as_float(r);
}

__global__ __launch_bounds__(256, 4) void lsh_kernel(
    const float* __restrict__ mat,
    const float* __restrict__ proj,
    int*         __restrict__ out)
{
    const int lane = threadIdx.x & 63;
    const int wid  = threadIdx.x >> 6;
    const int h    = lane & 15;            // chunk within row
    const int g    = lane >> 4;            // row within group

    // per-lane proj fragment: pf[j][r] = proj[(h*4+j)*8 + r]   (32 VGPRs)
    float pf[4][8];
    #pragma unroll
    for (int j = 0; j < 4; ++j) {
        const float4 a = *reinterpret_cast<const float4*>(proj + (h * 4 + j) * 8);
        const float4 b = *reinterpret_cast<const float4*>(proj + (h * 4 + j) * 8 + 4);
        pf[j][0] = a.x; pf[j][1] = a.y; pf[j][2] = a.z; pf[j][3] = a.w;
        pf[j][4] = b.x; pf[j][5] = b.y; pf[j][6] = b.z; pf[j][7] = b.w;
    }

    const bool m2 = (h >> 2) & 1;          // split selector: r-bit2
    const bool m1 = (h >> 1) & 1;          // split selector: r-bit1
    const bool m3 = (h >> 3) & 1;          // split selector: r-bit0
    const int  shift = (lane & 48);        // g*16, for the ballot slice

    const int gbase = (blockIdx.x * WPB + wid) * GPW;
    const float4* src = reinterpret_cast<const float4*>(mat);

    float4 v[U];
    #pragma unroll
    for (int u = 0; u < U; ++u)
        v[u] = src[(size_t)(gbase + u) * 64 + lane];

    #pragma unroll 1
    for (int it = 0; it < GPW; it += U) {
        float4 vn[U];
        const bool more = (it + U) < GPW;
        if (more) {
            #pragma unroll
            for (int u = 0; u < U; ++u)
                vn[u] = src[(size_t)(gbase + it + U + u) * 64 + lane];
        }

        #pragma unroll
        for (int u = 0; u < U; ++u) {
            const float vv[4] = {v[u].x, v[u].y, v[u].z, v[u].w};
            float s[8];
            #pragma unroll
            for (int r = 0; r < 8; ++r) {
                s[r] = vv[0] * pf[0][r];
                #pragma unroll
                for (int j = 1; j < 4; ++j)
                    s[r] = fmaf(vv[j], pf[j][r], s[r]);
            }
            // B: xor7 exchange, split r-bit2 by h2   (8 vals -> 4)
            float t[4];
            #pragma unroll
            for (int rp = 0; rp < 4; ++rp) {
                const float keep = m2 ? s[rp + 4] : s[rp];
                const float send = m2 ? s[rp]     : s[rp + 4];
                t[rp] = keep + dppf<DPP_XOR7>(send);
            }
            // C: xor2 exchange, split r-bit1 by h1   (4 -> 2)
            float q[2];
            #pragma unroll
            for (int rp = 0; rp < 2; ++rp) {
                const float keep = m1 ? t[rp + 2] : t[rp];
                const float send = m1 ? t[rp]     : t[rp + 2];
                q[rp] = keep + dppf<DPP_XOR2>(send);
            }
            // D: xor8 exchange, split r-bit0 by h3   (2 -> 1)
            {
                const float keep = m3 ? q[1] : q[0];
                const float send = m3 ? q[0] : q[1];
                q[0] = keep + dppf<DPP_XOR8>(send);
            }
            // E: xor1 final combine (full 16-chunk sum)
            const float f = q[0] + dppf<DPP_XOR1>(q[0]);

            // ballot -> 4 bins at once; lane h holds r = 4*h2 + 2*h1 + h3
            const unsigned long long bal = __ballot(f > 0.0f);
            const unsigned int w = (unsigned int)(bal >> shift);
            const unsigned int bin = (w & 0x55u) | ((w >> 7) & 0xAAu);
            const int bucket = (int)(bin ^ (bin >> 1));   // Gray-code table
            if (h == 0)
                out[(gbase + it + u) * 4 + g] = bucket;
        }

        #pragma unroll
        for (int u = 0; u < U; ++u) v[u] = vn[u];
    }
}

extern "C" void kernel_launch(void* const* d_in, const int* in_sizes, int n_in,
                              void* d_out, int out_size, void* d_ws, size_t ws_size,
                              hipStream_t stream) {
    const float* mat  = (const float*)d_in[0];   // [2,32,8192,64] f32
    const float* proj = (const float*)d_in[1];   // [1,1,64,8] f32
    // d_in[2] = perm (Gray code, computed analytically), d_in[3] = enc_vec
    int* out = (int*)d_out;                      // [524288] i32

    lsh_kernel<<<NBLK, 256, 0, stream>>>(mat, proj, out);
}

// Round 5
// 28.187 us; speedup vs baseline: 1.7429x; 1.0568x over previous
//
#include <hip/hip_runtime.h>

// buckets = gray( packbits( mat[row,:] @ proj[:,r] > 0 ) ),  gray(b) = b ^ (b>>1)
// mat: [2,32,8192,64] f32   proj: [64,8] f32   out: [524288] i32
//
// LDS-free: 16 lanes cooperate per row (lane = row g=lane>>4  x  chunk h=lane&15),
// each global_load_dwordx4 covers one 4-row group = 1 KiB fully coalesced.
// Per-lane partial dots vs a 32-VGPR proj fragment, then a value-splitting DPP
// butterfly (xor7, xor2, xor8 splits + xor1 combine) leaves lane h holding the
// full dot for r = 4*h2 + 2*h1 + h3; one __ballot yields 4 bins at once.
//
// R4 change: ring-buffered straight-line schedule. Two 4-group register tile
// sets (A, B) keep 8 KiB of loads in flight at all times; consume-then-refill
// lets the compiler emit counted vmcnt(4) waits -- no drain-to-zero point.

constexpr int D      = 64;
constexpr int ROWS   = 2 * 32 * 8192;      // 524288
constexpr int GROUPS = ROWS / 4;           // 131072 (4 rows / group)
constexpr int NBLK   = 2048;
constexpr int WPB    = 4;                  // 256 threads = 4 waves
constexpr int GPW    = GROUPS / (NBLK * WPB);  // 16 groups per wave

#define DPP_XOR1 0xB1    // quad_perm [1,0,3,2]
#define DPP_XOR2 0x4E    // quad_perm [2,3,0,1]
#define DPP_XOR7 0x141   // row_half_mirror
#define DPP_XOR8 0x128   // row_ror:8  (rotate by 8 within 16 == xor 8)

template <int CTRL>
__device__ __forceinline__ float dppf(float x) {
    const int xi = __float_as_int(x);
    const int r = __builtin_amdgcn_update_dpp(xi, xi, CTRL, 0xF, 0xF, false);
    return __int_as_float(r);
}

__global__ __launch_bounds__(256, 4) void lsh_kernel(
    const float* __restrict__ mat,
    const float* __restrict__ proj,
    int*         __restrict__ out)
{
    const int lane = threadIdx.x & 63;
    const int wid  = threadIdx.x >> 6;
    const int h    = lane & 15;            // chunk within row
    const int g    = lane >> 4;            // row within group

    // per-lane proj fragment: pf[j][r] = proj[(h*4+j)*8 + r]   (32 VGPRs)
    float pf[4][8];
    #pragma unroll
    for (int j = 0; j < 4; ++j) {
        const float4 a = *reinterpret_cast<const float4*>(proj + (h * 4 + j) * 8);
        const float4 b = *reinterpret_cast<const float4*>(proj + (h * 4 + j) * 8 + 4);
        pf[j][0] = a.x; pf[j][1] = a.y; pf[j][2] = a.z; pf[j][3] = a.w;
        pf[j][4] = b.x; pf[j][5] = b.y; pf[j][6] = b.z; pf[j][7] = b.w;
    }

    const bool m2 = (h >> 2) & 1;          // split selector: r-bit2
    const bool m1 = (h >> 1) & 1;          // split selector: r-bit1
    const bool m3 = (h >> 3) & 1;          // split selector: r-bit0
    const int  shift = (lane & 48);        // g*16, for the ballot slice

    const int gbase = (blockIdx.x * WPB + wid) * GPW;
    const float4* src = reinterpret_cast<const float4*>(mat) + (size_t)gbase * 64 + lane;

    float4 A[4], B[4];

    auto load4 = [&](float4 (&buf)[4], int base) {
        #pragma unroll
        for (int u = 0; u < 4; ++u)
            buf[u] = src[(base + u) * 64];          // 1 KiB apart: imm offsets
    };

    auto compute4 = [&](const float4 (&buf)[4], int base) {
        #pragma unroll
        for (int u = 0; u < 4; ++u) {
            const float vv[4] = {buf[u].x, buf[u].y, buf[u].z, buf[u].w};
            float s[8];
            #pragma unroll
            for (int r = 0; r < 8; ++r) {
                s[r] = vv[0] * pf[0][r];
                #pragma unroll
                for (int j = 1; j < 4; ++j)
                    s[r] = fmaf(vv[j], pf[j][r], s[r]);
            }
            // B: xor7 exchange, split r-bit2 by h2   (8 vals -> 4)
            float t[4];
            #pragma unroll
            for (int rp = 0; rp < 4; ++rp) {
                const float keep = m2 ? s[rp + 4] : s[rp];
                const float send = m2 ? s[rp]     : s[rp + 4];
                t[rp] = keep + dppf<DPP_XOR7>(send);
            }
            // C: xor2 exchange, split r-bit1 by h1   (4 -> 2)
            float q[2];
            #pragma unroll
            for (int rp = 0; rp < 2; ++rp) {
                const float keep = m1 ? t[rp + 2] : t[rp];
                const float send = m1 ? t[rp]     : t[rp + 2];
                q[rp] = keep + dppf<DPP_XOR2>(send);
            }
            // D: xor8 exchange, split r-bit0 by h3   (2 -> 1)
            {
                const float keep = m3 ? q[1] : q[0];
                const float send = m3 ? q[0] : q[1];
                q[0] = keep + dppf<DPP_XOR8>(send);
            }
            // E: xor1 final combine (full 16-chunk sum)
            const float f = q[0] + dppf<DPP_XOR1>(q[0]);

            // ballot -> 4 bins at once; lane h holds r = 4*h2 + 2*h1 + h3
            const unsigned long long bal = __ballot(f > 0.0f);
            const unsigned int w = (unsigned int)(bal >> shift);
            const unsigned int bin = (w & 0x55u) | ((w >> 7) & 0xAAu);
            const int bucket = (int)(bin ^ (bin >> 1));   // Gray-code table
            if (h == 0)
                out[(gbase + base + u) * 4 + g] = bucket;
        }
    };

    // straight-line ring schedule: 8 KiB in flight while computing
    load4(A, 0);                // groups 0..3
    load4(B, 4);                // groups 4..7
    compute4(A, 0);             // waits vmcnt(4): only A drained
    load4(A, 8);                // refill -> 8 KiB in flight again
    compute4(B, 4);             // waits vmcnt(4)
    load4(B, 12);
    compute4(A, 8);             // waits vmcnt(4)
    compute4(B, 12);            // final drain

    (void)ROWS; (void)GROUPS;
}

extern "C" void kernel_launch(void* const* d_in, const int* in_sizes, int n_in,
                              void* d_out, int out_size, void* d_ws, size_t ws_size,
                              hipStream_t stream) {
    const float* mat  = (const float*)d_in[0];   // [2,32,8192,64] f32
    const float* proj = (const float*)d_in[1];   // [1,1,64,8] f32
    // d_in[2] = perm (Gray code, computed analytically), d_in[3] = enc_vec
    int* out = (int*)d_out;                      // [524288] i32

    lsh_kernel<<<NBLK, 256, 0, stream>>>(mat, proj, out);
}